// Round 2
// 211.047 us; speedup vs baseline: 1.0848x; 1.0848x over previous
//
#include <hip/hip_runtime.h>

#define BB  4
#define CC  64
#define HH  128
#define WW  128
#define KS  21
#define PAD 10
#define HWs (HH*WW)
#define LROW 160           // 128 cols + 12 left pad + 20 right pad
#define LBUF (8*LROW)      // floats per buffer (8 rows)

typedef float f32x4n __attribute__((ext_vector_type(4)));  // native vec for nontemporal store

// Block: 256 threads = 8 rows x 32 pixel-quads, one di, all 21 dj.
// f2 rows double-buffered in LDS; wave w owns rows {2w,2w+1} only ->
// all LDS sharing is intra-wave: NO barriers needed (DS ops of a wave
// execute in order; sched_barrier(0) stops compiler reordering DS ops
// that alias only across lanes).
__global__ __launch_bounds__(256, 3) void corr_kernel(
    const float* __restrict__ feat1,
    const float* __restrict__ feat2,
    float* __restrict__ out)
{
    __shared__ __align__(16) float lds[2*LBUF];

    const int tid = threadIdx.x;
    int bi = blockIdx.x;
    const int di = bi % KS;  bi /= KS;
    const int h8 = bi % (HH/8);
    const int b  = bi / (HH/8);

    const int row = tid >> 5;        // 0..7 within octet
    const int q   = tid & 31;
    const int h   = h8*8 + row;
    const int w0  = q << 2;          // 4 consecutive pixels
    const int rr  = h + di - PAD;    // feat2 source row
    const bool valid = (rr >= 0) && (rr < HH);

    // zero the pad columns (L in [0,12) U [140,160)) of this wave's rows, both buffers
    {
        const int L = (q < 12) ? q : (q + 128);
        lds[row*LROW + L]        = 0.0f;
        lds[LBUF + row*LROW + L] = 0.0f;
    }

    float acc[4][KS];
#pragma unroll
    for (int p = 0; p < 4; ++p)
#pragma unroll
        for (int d = 0; d < KS; ++d) acc[p][d] = 0.0f;

    if (__ballot(valid) != 0ull) {
        const float* f1p = feat1 + (((ptrdiff_t)b*CC*HH + h)*WW + w0);
        const float* f2p = feat2 + (((ptrdiff_t)b*CC*HH + rr)*WW + w0);

        float*       lw = &lds[row*LROW + 12 + w0];   // stage: cols [w0,w0+4) at L=w0+12
        const float* lr = &lds[row*LROW + w0];        // read base: L=w0 corresponds to col w0-12

        const bool in0 = valid && (w0 >= 12);   // cols w0-10..w0-9
        const bool in1 = valid && (w0 >= 8);    // cols w0-8..w0-5

        float4 vcur = make_float4(0.f,0.f,0.f,0.f);
        float4 vnxt = make_float4(0.f,0.f,0.f,0.f);
        float2 g0   = make_float2(0.f,0.f);
        float4 g1   = make_float4(0.f,0.f,0.f,0.f);
        if (valid) {
            vcur = *(const float4*)(f2p);
            vnxt = *(const float4*)(f2p + HWs);
        }
        if (in0) g0 = *(const float2*)(f2p - 10);
        if (in1) g1 = *(const float4*)(f2p - 8);
        float4 a = *(const float4*)(f1p);

        *(float4*)lw = vcur;                    // stage c=0 into buf0
        __builtin_amdgcn_sched_barrier(0);      // pad/stage writes precede all window reads

#pragma unroll 2
        for (int c = 0; c < CC; ++c) {
            // ---- global prefetch for next iteration (issue early) ----
            float4 an  = a;
            float2 g0n = make_float2(0.f,0.f);
            float4 g1n = make_float4(0.f,0.f,0.f,0.f);
            float4 vld = make_float4(0.f,0.f,0.f,0.f);
            if (c + 1 < CC) {
                an = *(const float4*)(f1p + HWs);
                if (in0) g0n = *(const float2*)(f2p + HWs - 10);
                if (in1) g1n = *(const float4*)(f2p + HWs - 8);
                if (valid && (c + 2 < CC)) vld = *(const float4*)(f2p + 2*HWs);
            }

            // ---- LDS window for current c (contiguous, conflict-free) ----
            const float* lrb = lr + ((c & 1) ? LBUF : 0);
            const float4 w08 = *(const float4*)(lrb + 8);    // cols w0-4 .. w0-1
            const float4 w16 = *(const float4*)(lrb + 16);   // cols w0+4 .. w0+7
            const float4 w20 = *(const float4*)(lrb + 20);   // cols w0+8 .. w0+11
            const float2 w24 = *(const float2*)(lrb + 24);   // cols w0+12, w0+13

            // ---- stage c+1 into the other buffer ----
            *(float4*)(lw + ((c & 1) ? 0 : LBUF)) = vnxt;
            __builtin_amdgcn_sched_barrier(0);   // separate this write from next iter's reads

            // win[i] = f2 col (w0-12+i); indices 2..25 used
            float win[28];
            win[2]=g0.x;   win[3]=g0.y;
            win[4]=g1.x;   win[5]=g1.y;   win[6]=g1.z;   win[7]=g1.w;
            win[8]=w08.x;  win[9]=w08.y;  win[10]=w08.z; win[11]=w08.w;
            win[12]=vcur.x; win[13]=vcur.y; win[14]=vcur.z; win[15]=vcur.w; // own quad: reuse regs
            win[16]=w16.x; win[17]=w16.y; win[18]=w16.z; win[19]=w16.w;
            win[20]=w20.x; win[21]=w20.y; win[22]=w20.z; win[23]=w20.w;
            win[24]=w24.x; win[25]=w24.y;

#pragma unroll
            for (int d = 0; d < KS; ++d) {
                acc[0][d] += a.x * win[d + 2];
                acc[1][d] += a.y * win[d + 3];
                acc[2][d] += a.z * win[d + 4];
                acc[3][d] += a.w * win[d + 5];
            }

            a = an; g0 = g0n; g1 = g1n; vcur = vnxt; vnxt = vld;
            f1p += HWs; f2p += HWs;
        }
    }

    const float scale = 1.0f / (float)CC;
    float* op = out + ((((ptrdiff_t)b*(KS*KS) + di*KS)*HH + h)*WW + w0);
#pragma unroll
    for (int d = 0; d < KS; ++d) {
        f32x4n v = { acc[0][d]*scale, acc[1][d]*scale,
                     acc[2][d]*scale, acc[3][d]*scale };
        __builtin_nontemporal_store(v, (f32x4n*)(op + (ptrdiff_t)d*HWs));
    }
}

extern "C" void kernel_launch(void* const* d_in, const int* in_sizes, int n_in,
                              void* d_out, int out_size, void* d_ws, size_t ws_size,
                              hipStream_t stream) {
    const float* feat1 = (const float*)d_in[0];
    const float* feat2 = (const float*)d_in[1];
    float* out = (float*)d_out;

    const int blocks = BB * (HH / 8) * KS;   // 4 * 16 * 21 = 1344
    corr_kernel<<<blocks, 256, 0, stream>>>(feat1, feat2, out);
}